// Round 10
// baseline (118.187 us; speedup 1.0000x reference)
//
#include <hip/hip_runtime.h>
#include <hip/hip_cooperative_groups.h>

// YOLO loss forward, MI355X. Memory-bound streaming reduction.
// R10: single COOPERATIVE dispatch. Main loop identical to R8 (3-deep
//     counted-vmcnt pipeline, CPB=64, 46 KB LDS, GRID=768 = 3 blocks/CU x 256
//     CU -> co-resident). Block partials -> d_ws (agent-scope atomic stores),
//     grid.sync(), block 0 reduces 768 partials, thread 0 writes d_out.
//     No hipMemsetAsync (R9 lesson: a 4-byte memset node costs ~10 us),
//     no float-atomic accumulation (absmax stays 0), deterministic.
// LESSONS carried: (R6) global_load_lds writes in 16-lane groups -- active
//     lane count must be ≡0 (mod 16), contiguous from lane 0, within buffer.
//     (T4) every wave issues the SAME gload count per stage for vmcnt(N).
//     (R9) never hipMemsetAsync in the timed path.

namespace cg = cooperative_groups;

constexpr int N_IMG  = 2048;
constexpr int NC     = 30;
constexpr int CELLS  = N_IMG * 14 * 14;   // 401408
constexpr int BLOCK  = 256;
constexpr int CPB    = 64;                // cells per chunk
constexpr int NCHT   = CELLS / CPB;       // 6272 total chunks
constexpr int GRID   = 768;               // 3 blocks/CU (46 KB LDS each)
constexpr float INV14 = 1.0f / 14.0f;

constexpr int FPB   = 2 * CPB * NC;       // floats per buffer (pred+targ) = 3840
constexpr int SLOTS = FPB / 4;            // 960 float4 slots per buffer
constexpr int SPW   = SLOTS / 4;          // 240 slots per wave
constexpr int PREDS = CPB * NC / 4;       // 480 pred slots

__device__ __forceinline__ void gload16(const void* g, void* l) {
    __builtin_amdgcn_global_load_lds(
        (const __attribute__((address_space(1))) void*)g,
        (__attribute__((address_space(3))) void*)l, 16, 0, 0);
}

__device__ __forceinline__ float cell_loss(const float* __restrict__ cp,
                                           const float* __restrict__ ct)
{
    float pv[NC], tv[NC];
    const float2* p2 = reinterpret_cast<const float2*>(cp);  // 8B-aligned
    const float2* t2 = reinterpret_cast<const float2*>(ct);
    #pragma unroll
    for (int i = 0; i < NC / 2; ++i) {
        float2 a = p2[i]; pv[2*i] = a.x; pv[2*i+1] = a.y;
        float2 b = t2[i]; tv[2*i] = b.x; tv[2*i+1] = b.y;
    }

    const float coo = (tv[4] > 0.0f) ? 1.0f : 0.0f;

    const float txc = tv[0] * INV14, tyc = tv[1] * INV14;
    const float tx1 = txc - 0.5f * tv[2], ty1 = tyc - 0.5f * tv[3];
    const float tx2 = txc + 0.5f * tv[2], ty2 = tyc + 0.5f * tv[3];
    const float t_area = (tx2 - tx1) * (ty2 - ty1);

    float i0, u0;
    {
        const float xc = pv[0] * INV14, yc = pv[1] * INV14;
        const float x1 = xc - 0.5f * pv[2], y1 = yc - 0.5f * pv[3];
        const float x2 = xc + 0.5f * pv[2], y2 = yc + 0.5f * pv[3];
        const float a1 = (x2 - x1) * (y2 - y1);
        const float wx = fmaxf(fminf(x2, tx2) - fmaxf(x1, tx1), 0.0f);
        const float wy = fmaxf(fminf(y2, ty2) - fmaxf(y1, ty1), 0.0f);
        i0 = wx * wy;
        u0 = a1 + t_area - i0;            // > 0 (w,h >= 0.05)
    }
    float i1, u1;
    {
        const float xc = pv[5] * INV14, yc = pv[6] * INV14;
        const float x1 = xc - 0.5f * pv[7], y1 = yc - 0.5f * pv[8];
        const float x2 = xc + 0.5f * pv[7], y2 = yc + 0.5f * pv[8];
        const float a1 = (x2 - x1) * (y2 - y1);
        const float wx = fmaxf(fminf(x2, tx2) - fmaxf(x1, tx1), 0.0f);
        const float wy = fmaxf(fminf(y2, ty2) - fmaxf(y1, ty1), 0.0f);
        i1 = wx * wy;
        u1 = a1 + t_area - i1;
    }

    // argmax first-max tie-break, divide-free: iou1 > iou0 <=> i1*u0 > i0*u1
    const bool sel = (i1 * u0) > (i0 * u1);
    const float rp0 = sel ? pv[5] : pv[0];
    const float rp1 = sel ? pv[6] : pv[1];
    const float rp2 = sel ? pv[7] : pv[2];
    const float rp3 = sel ? pv[8] : pv[3];
    const float rp4 = sel ? pv[9] : pv[4];
    const float rt0 = sel ? tv[5] : tv[0];
    const float rt1 = sel ? tv[6] : tv[1];
    const float rt2 = sel ? tv[7] : tv[2];
    const float rt3 = sel ? tv[8] : tv[3];
    const float nrp4 = sel ? pv[4] : pv[9];

    const float d0 = rp0 - rt0, d1 = rp1 - rt1;
    const float d2 = sqrtf(rp2) - sqrtf(rt2);
    const float d3 = sqrtf(rp3) - sqrtf(rt3);
    const float loc     = d0*d0 + d1*d1 + d2*d2 + d3*d3;
    const float contain = rp4 * rp4;
    const float notc    = nrp4 * nrp4;
    const float e4 = pv[4] - tv[4], e9 = pv[9] - tv[9];
    const float noobj = e4*e4 + e9*e9;
    float cls = 0.0f;
    #pragma unroll
    for (int c = 10; c < NC; ++c) { const float d = pv[c] - tv[c]; cls += d*d; }

    return coo * (5.0f * loc + 2.0f * contain + notc + cls)
         + (1.0f - coo) * (0.5f * noobj);
}

__global__ __launch_bounds__(BLOCK)
void yolo_coop(const float* __restrict__ pred,
               const float* __restrict__ targ,
               float* __restrict__ out,
               float* __restrict__ partial)
{
    // buffer layout: floats [0,1920) = pred chunk, [1920,3840) = targ chunk
    __shared__ float sbuf[3 * FPB];       // 3 x 15360 B = 46 KB -> 3 blocks/CU

    const int tid = threadIdx.x;
    const int bid = blockIdx.x;
    const int wv  = tid >> 6;
    const int ln  = tid & 63;

    // stage chunk into lbuf. Per-wave contiguous 240-slot segment:
    // 3 full 64-lane rounds + one 48-lane round (3 x 16-groups from lane 0).
    // EVERY wave issues exactly 4 gloads -> uniform vmcnt accounting.
    auto stage = [&](float* lbuf, int chunk) {
        const size_t fbase = (size_t)chunk * (size_t)(CPB * NC);
        const int wbase = wv * SPW;       // 0,240,480,720
        const float4* gsrc = (wv < 2)
            ? reinterpret_cast<const float4*>(pred + fbase) + wbase
            : reinterpret_cast<const float4*>(targ + fbase) + (wbase - PREDS);
        float4* lb = reinterpret_cast<float4*>(lbuf) + wbase;
        #pragma unroll
        for (int i = 0; i < 3; ++i)
            gload16(gsrc + i * 64 + ln, lb + i * 64 + ln);
        if (ln < 48)
            gload16(gsrc + 192 + ln, lb + 192 + ln);
    };

    const int n = (NCHT - bid + GRID - 1) / GRID;   // 9 (bid<128) or 8

    // prologue: fill buffers 0,1 (8 outstanding); wait oldest 4 -> buf0 ready
    stage(sbuf, bid);
    stage(sbuf + FPB, bid + GRID);
    asm volatile("s_waitcnt vmcnt(4)" ::: "memory");
    __builtin_amdgcn_sched_barrier(0);
    __builtin_amdgcn_s_barrier();
    __builtin_amdgcn_sched_barrier(0);

    float acc = 0.0f;
    for (int k = 0; k < n; ++k) {
        const bool pre = (k + 2 < n);
        if (pre) stage(sbuf + ((k + 2) % 3) * FPB, bid + (k + 2) * GRID);

        if (tid < CPB) {
            const float* b = sbuf + (k % 3) * FPB;
            acc += cell_loss(b + tid * NC, b + CPB * NC + tid * NC);
        }

        // certify buf[k+1] complete; keep buf[k+2]'s 4 loads in flight
        if (pre) asm volatile("s_waitcnt vmcnt(4)" ::: "memory");
        else     asm volatile("s_waitcnt vmcnt(0)" ::: "memory");
        __builtin_amdgcn_sched_barrier(0);
        __builtin_amdgcn_s_barrier();
        __builtin_amdgcn_sched_barrier(0);
    }

    // block reduction -> partial[bid] (agent-scope store: cross-XCD visible)
    __shared__ float wsum[BLOCK / 64];
    #pragma unroll
    for (int o = 32; o > 0; o >>= 1) acc += __shfl_down(acc, o, 64);
    if ((tid & 63) == 0) wsum[tid >> 6] = acc;
    __syncthreads();
    if (tid == 0)
        __hip_atomic_store(&partial[bid],
                           wsum[0] + wsum[1] + wsum[2] + wsum[3],
                           __ATOMIC_RELAXED, __HIP_MEMORY_SCOPE_AGENT);

    cg::this_grid().sync();               // completion + device-scope visibility

    // block 0: reduce 768 partials, write the single output
    if (bid == 0) {
        double s = 0.0;
        #pragma unroll
        for (int i = 0; i < GRID / BLOCK; ++i)
            s += (double)__hip_atomic_load(&partial[tid + i * BLOCK],
                                           __ATOMIC_RELAXED,
                                           __HIP_MEMORY_SCOPE_AGENT);
        #pragma unroll
        for (int o = 32; o > 0; o >>= 1) s += __shfl_down(s, o, 64);
        __shared__ double w[BLOCK / 64];
        if ((tid & 63) == 0) w[tid >> 6] = s;
        __syncthreads();
        if (tid == 0)
            out[0] = (float)((w[0] + w[1] + w[2] + w[3]) / (double)N_IMG);
    }
}

extern "C" void kernel_launch(void* const* d_in, const int* in_sizes, int n_in,
                              void* d_out, int out_size, void* d_ws, size_t ws_size,
                              hipStream_t stream)
{
    const float* pred = (const float*)d_in[0];
    const float* targ = (const float*)d_in[1];
    float* out        = (float*)d_out;
    float* partial    = (float*)d_ws;   // 768 floats = 3 KB

    void* args[] = {(void*)&pred, (void*)&targ, (void*)&out, (void*)&partial};
    hipLaunchCooperativeKernel((void*)yolo_coop, dim3(GRID), dim3(BLOCK),
                               args, 0, stream);
}

// Round 11
// 33.109 us; speedup vs baseline: 3.5696x; 3.5696x over previous
//
#include <hip/hip_runtime.h>

// YOLO loss forward, MI355X. Memory-bound streaming reduction.
// R11: R8 main kernel bit-identical in the hot loop; finish is one
//     atomicAdd(out, blocksum/N) per block (validated absmax 0.0 in R4).
//     A 1-THREAD zero-kernel node precedes it (kernel nodes ~1us; R9's
//     lesson: hipMemsetAsync NODES cost ~10us; R10's lesson: cooperative
//     grid.sync costs ~85us -- both banned).
// LESSONS carried: (R6) global_load_lds writes in 16-lane groups -- active
//     lane count must be ≡0 (mod 16), contiguous from lane 0, within buffer.
//     (T4) every wave issues the SAME gload count per stage for vmcnt(N).

constexpr int N_IMG  = 2048;
constexpr int NC     = 30;
constexpr int CELLS  = N_IMG * 14 * 14;   // 401408
constexpr int BLOCK  = 256;
constexpr int CPB    = 64;                // cells per chunk
constexpr int NCHT   = CELLS / CPB;       // 6272 total chunks
constexpr int GRID   = 768;               // 3 blocks/CU (46 KB LDS each)
constexpr float INV14 = 1.0f / 14.0f;
constexpr float INVN  = 1.0f / (float)N_IMG;

constexpr int FPB   = 2 * CPB * NC;       // floats per buffer (pred+targ) = 3840
constexpr int SLOTS = FPB / 4;            // 960 float4 slots per buffer
constexpr int SPW   = SLOTS / 4;          // 240 slots per wave
constexpr int PREDS = CPB * NC / 4;       // 480 pred slots

__device__ __forceinline__ void gload16(const void* g, void* l) {
    __builtin_amdgcn_global_load_lds(
        (const __attribute__((address_space(1))) void*)g,
        (__attribute__((address_space(3))) void*)l, 16, 0, 0);
}

__device__ __forceinline__ float cell_loss(const float* __restrict__ cp,
                                           const float* __restrict__ ct)
{
    float pv[NC], tv[NC];
    const float2* p2 = reinterpret_cast<const float2*>(cp);  // 8B-aligned
    const float2* t2 = reinterpret_cast<const float2*>(ct);
    #pragma unroll
    for (int i = 0; i < NC / 2; ++i) {
        float2 a = p2[i]; pv[2*i] = a.x; pv[2*i+1] = a.y;
        float2 b = t2[i]; tv[2*i] = b.x; tv[2*i+1] = b.y;
    }

    const float coo = (tv[4] > 0.0f) ? 1.0f : 0.0f;

    const float txc = tv[0] * INV14, tyc = tv[1] * INV14;
    const float tx1 = txc - 0.5f * tv[2], ty1 = tyc - 0.5f * tv[3];
    const float tx2 = txc + 0.5f * tv[2], ty2 = tyc + 0.5f * tv[3];
    const float t_area = (tx2 - tx1) * (ty2 - ty1);

    float i0, u0;
    {
        const float xc = pv[0] * INV14, yc = pv[1] * INV14;
        const float x1 = xc - 0.5f * pv[2], y1 = yc - 0.5f * pv[3];
        const float x2 = xc + 0.5f * pv[2], y2 = yc + 0.5f * pv[3];
        const float a1 = (x2 - x1) * (y2 - y1);
        const float wx = fmaxf(fminf(x2, tx2) - fmaxf(x1, tx1), 0.0f);
        const float wy = fmaxf(fminf(y2, ty2) - fmaxf(y1, ty1), 0.0f);
        i0 = wx * wy;
        u0 = a1 + t_area - i0;            // > 0 (w,h >= 0.05)
    }
    float i1, u1;
    {
        const float xc = pv[5] * INV14, yc = pv[6] * INV14;
        const float x1 = xc - 0.5f * pv[7], y1 = yc - 0.5f * pv[8];
        const float x2 = xc + 0.5f * pv[7], y2 = yc + 0.5f * pv[8];
        const float a1 = (x2 - x1) * (y2 - y1);
        const float wx = fmaxf(fminf(x2, tx2) - fmaxf(x1, tx1), 0.0f);
        const float wy = fmaxf(fminf(y2, ty2) - fmaxf(y1, ty1), 0.0f);
        i1 = wx * wy;
        u1 = a1 + t_area - i1;
    }

    // argmax first-max tie-break, divide-free: iou1 > iou0 <=> i1*u0 > i0*u1
    const bool sel = (i1 * u0) > (i0 * u1);
    const float rp0 = sel ? pv[5] : pv[0];
    const float rp1 = sel ? pv[6] : pv[1];
    const float rp2 = sel ? pv[7] : pv[2];
    const float rp3 = sel ? pv[8] : pv[3];
    const float rp4 = sel ? pv[9] : pv[4];
    const float rt0 = sel ? tv[5] : tv[0];
    const float rt1 = sel ? tv[6] : tv[1];
    const float rt2 = sel ? tv[7] : tv[2];
    const float rt3 = sel ? tv[8] : tv[3];
    const float nrp4 = sel ? pv[4] : pv[9];

    const float d0 = rp0 - rt0, d1 = rp1 - rt1;
    const float d2 = sqrtf(rp2) - sqrtf(rt2);
    const float d3 = sqrtf(rp3) - sqrtf(rt3);
    const float loc     = d0*d0 + d1*d1 + d2*d2 + d3*d3;
    const float contain = rp4 * rp4;
    const float notc    = nrp4 * nrp4;
    const float e4 = pv[4] - tv[4], e9 = pv[9] - tv[9];
    const float noobj = e4*e4 + e9*e9;
    float cls = 0.0f;
    #pragma unroll
    for (int c = 10; c < NC; ++c) { const float d = pv[c] - tv[c]; cls += d*d; }

    return coo * (5.0f * loc + 2.0f * contain + notc + cls)
         + (1.0f - coo) * (0.5f * noobj);
}

__global__ void yolo_zero(float* __restrict__ out) { out[0] = 0.0f; }

__global__ __launch_bounds__(BLOCK)
void yolo_main(const float* __restrict__ pred,
               const float* __restrict__ targ,
               float* __restrict__ out)
{
    // buffer layout: floats [0,1920) = pred chunk, [1920,3840) = targ chunk
    __shared__ float sbuf[3 * FPB];       // 3 x 15360 B = 46 KB -> 3 blocks/CU

    const int tid = threadIdx.x;
    const int bid = blockIdx.x;
    const int wv  = tid >> 6;
    const int ln  = tid & 63;

    // stage chunk into lbuf. Per-wave contiguous 240-slot segment:
    // 3 full 64-lane rounds + one 48-lane round (3 x 16-groups from lane 0).
    // EVERY wave issues exactly 4 gloads -> uniform vmcnt accounting.
    auto stage = [&](float* lbuf, int chunk) {
        const size_t fbase = (size_t)chunk * (size_t)(CPB * NC);
        const int wbase = wv * SPW;       // 0,240,480,720
        const float4* gsrc = (wv < 2)
            ? reinterpret_cast<const float4*>(pred + fbase) + wbase
            : reinterpret_cast<const float4*>(targ + fbase) + (wbase - PREDS);
        float4* lb = reinterpret_cast<float4*>(lbuf) + wbase;
        #pragma unroll
        for (int i = 0; i < 3; ++i)
            gload16(gsrc + i * 64 + ln, lb + i * 64 + ln);
        if (ln < 48)
            gload16(gsrc + 192 + ln, lb + 192 + ln);
    };

    const int n = (NCHT - bid + GRID - 1) / GRID;   // 9 (bid<128) or 8

    // prologue: fill buffers 0,1 (8 outstanding); wait oldest 4 -> buf0 ready
    stage(sbuf, bid);
    stage(sbuf + FPB, bid + GRID);
    asm volatile("s_waitcnt vmcnt(4)" ::: "memory");
    __builtin_amdgcn_sched_barrier(0);
    __builtin_amdgcn_s_barrier();
    __builtin_amdgcn_sched_barrier(0);

    float acc = 0.0f;
    for (int k = 0; k < n; ++k) {
        const bool pre = (k + 2 < n);
        if (pre) stage(sbuf + ((k + 2) % 3) * FPB, bid + (k + 2) * GRID);

        if (tid < CPB) {
            const float* b = sbuf + (k % 3) * FPB;
            acc += cell_loss(b + tid * NC, b + CPB * NC + tid * NC);
        }

        // certify buf[k+1] complete; keep buf[k+2]'s 4 loads in flight
        if (pre) asm volatile("s_waitcnt vmcnt(4)" ::: "memory");
        else     asm volatile("s_waitcnt vmcnt(0)" ::: "memory");
        __builtin_amdgcn_sched_barrier(0);
        __builtin_amdgcn_s_barrier();
        __builtin_amdgcn_sched_barrier(0);
    }

    // block reduction + one device-scope atomic per block (no trailing node)
    __shared__ float wsum[BLOCK / 64];
    #pragma unroll
    for (int o = 32; o > 0; o >>= 1) acc += __shfl_down(acc, o, 64);
    if ((tid & 63) == 0) wsum[tid >> 6] = acc;
    __syncthreads();
    if (tid == 0)
        atomicAdd(out, (wsum[0] + wsum[1] + wsum[2] + wsum[3]) * INVN);
}

extern "C" void kernel_launch(void* const* d_in, const int* in_sizes, int n_in,
                              void* d_out, int out_size, void* d_ws, size_t ws_size,
                              hipStream_t stream)
{
    const float* pred = (const float*)d_in[0];
    const float* targ = (const float*)d_in[1];
    float* out        = (float*)d_out;

    yolo_zero<<<1, 1, 0, stream>>>(out);             // cheap kernel node, not memset
    yolo_main<<<GRID, BLOCK, 0, stream>>>(pred, targ, out);
}

// Round 12
// 24.284 us; speedup vs baseline: 4.8669x; 1.3634x over previous
//
#include <hip/hip_runtime.h>

// YOLO loss forward, MI355X. Memory-bound streaming reduction.
// R12: R8 pipeline with doubled TLP: CPB=32, 3 buffers x 7.68 KB = 23 KB LDS
//     -> 6 blocks/CU, GRID=1536. Counted vmcnt(2) (2 gloads/stage/wave,
//     uniform across waves). Partials + trailing small final kernel (R8
//     structure -- atomics/memset/coop all measured worse: R9/R10/R11).
// LESSONS carried: (R6) global_load_lds writes in 16-lane groups -- active
//     lane count must be ≡0 (mod 16), contiguous from lane 0, within buffer.
//     (T4) every wave issues the SAME gload count per stage for vmcnt(N).
//     (R9/R11) no hipMemsetAsync nodes, no same-address atomic finish.
//     (R10) no cooperative grid.sync (~85us).

constexpr int N_IMG  = 2048;
constexpr int NC     = 30;
constexpr int CELLS  = N_IMG * 14 * 14;   // 401408
constexpr int BLOCK  = 256;
constexpr int CPB    = 32;                // cells per chunk
constexpr int NCHT   = CELLS / CPB;       // 12544 total chunks
constexpr int GRID   = 1536;              // 6 blocks/CU (23 KB LDS each)
constexpr float INV14 = 1.0f / 14.0f;

constexpr int FPBF  = 2 * CPB * NC;       // floats per buffer (pred+targ) = 1920
constexpr int SLOTS = FPBF / 4;           // 480 float4 slots per buffer
constexpr int PREDS = CPB * NC / 4;       // 240 pred slots

__device__ __forceinline__ void gload16(const void* g, void* l) {
    __builtin_amdgcn_global_load_lds(
        (const __attribute__((address_space(1))) void*)g,
        (__attribute__((address_space(3))) void*)l, 16, 0, 0);
}

__device__ __forceinline__ float cell_loss(const float* __restrict__ cp,
                                           const float* __restrict__ ct)
{
    float pv[NC], tv[NC];
    const float2* p2 = reinterpret_cast<const float2*>(cp);  // 8B-aligned
    const float2* t2 = reinterpret_cast<const float2*>(ct);
    #pragma unroll
    for (int i = 0; i < NC / 2; ++i) {
        float2 a = p2[i]; pv[2*i] = a.x; pv[2*i+1] = a.y;
        float2 b = t2[i]; tv[2*i] = b.x; tv[2*i+1] = b.y;
    }

    const float coo = (tv[4] > 0.0f) ? 1.0f : 0.0f;

    const float txc = tv[0] * INV14, tyc = tv[1] * INV14;
    const float tx1 = txc - 0.5f * tv[2], ty1 = tyc - 0.5f * tv[3];
    const float tx2 = txc + 0.5f * tv[2], ty2 = tyc + 0.5f * tv[3];
    const float t_area = (tx2 - tx1) * (ty2 - ty1);

    float i0, u0;
    {
        const float xc = pv[0] * INV14, yc = pv[1] * INV14;
        const float x1 = xc - 0.5f * pv[2], y1 = yc - 0.5f * pv[3];
        const float x2 = xc + 0.5f * pv[2], y2 = yc + 0.5f * pv[3];
        const float a1 = (x2 - x1) * (y2 - y1);
        const float wx = fmaxf(fminf(x2, tx2) - fmaxf(x1, tx1), 0.0f);
        const float wy = fmaxf(fminf(y2, ty2) - fmaxf(y1, ty1), 0.0f);
        i0 = wx * wy;
        u0 = a1 + t_area - i0;            // > 0 (w,h >= 0.05)
    }
    float i1, u1;
    {
        const float xc = pv[5] * INV14, yc = pv[6] * INV14;
        const float x1 = xc - 0.5f * pv[7], y1 = yc - 0.5f * pv[8];
        const float x2 = xc + 0.5f * pv[7], y2 = yc + 0.5f * pv[8];
        const float a1 = (x2 - x1) * (y2 - y1);
        const float wx = fmaxf(fminf(x2, tx2) - fmaxf(x1, tx1), 0.0f);
        const float wy = fmaxf(fminf(y2, ty2) - fmaxf(y1, ty1), 0.0f);
        i1 = wx * wy;
        u1 = a1 + t_area - i1;
    }

    // argmax first-max tie-break, divide-free: iou1 > iou0 <=> i1*u0 > i0*u1
    const bool sel = (i1 * u0) > (i0 * u1);
    const float rp0 = sel ? pv[5] : pv[0];
    const float rp1 = sel ? pv[6] : pv[1];
    const float rp2 = sel ? pv[7] : pv[2];
    const float rp3 = sel ? pv[8] : pv[3];
    const float rp4 = sel ? pv[9] : pv[4];
    const float rt0 = sel ? tv[5] : tv[0];
    const float rt1 = sel ? tv[6] : tv[1];
    const float rt2 = sel ? tv[7] : tv[2];
    const float rt3 = sel ? tv[8] : tv[3];
    const float nrp4 = sel ? pv[4] : pv[9];

    const float d0 = rp0 - rt0, d1 = rp1 - rt1;
    const float d2 = sqrtf(rp2) - sqrtf(rt2);
    const float d3 = sqrtf(rp3) - sqrtf(rt3);
    const float loc     = d0*d0 + d1*d1 + d2*d2 + d3*d3;
    const float contain = rp4 * rp4;
    const float notc    = nrp4 * nrp4;
    const float e4 = pv[4] - tv[4], e9 = pv[9] - tv[9];
    const float noobj = e4*e4 + e9*e9;
    float cls = 0.0f;
    #pragma unroll
    for (int c = 10; c < NC; ++c) { const float d = pv[c] - tv[c]; cls += d*d; }

    return coo * (5.0f * loc + 2.0f * contain + notc + cls)
         + (1.0f - coo) * (0.5f * noobj);
}

__global__ __launch_bounds__(BLOCK)
void yolo_main(const float* __restrict__ pred,
               const float* __restrict__ targ,
               float* __restrict__ partial)
{
    // buffer layout (float4 slots): [0,240) = pred chunk, [240,480) = targ.
    __shared__ float sbuf[3 * FPBF];      // 3 x 7680 B = 23 KB -> 6 blocks/CU

    const int tid = threadIdx.x;
    const int bid = blockIdx.x;
    const int wv  = tid >> 6;
    const int ln  = tid & 63;

    // Wave slot segments: w0 [0,128), w1 [128,256), w2 [256,368), w3 [368,480).
    // Every wave issues EXACTLY 2 gloads/stage (w0/w1: 2 full rounds;
    // w2/w3: 64-lane + 48-lane rounds; 48 ≡ 0 mod 16, from lane 0 -- R6-safe).
    // Per-lane pred/targ src select is legal: only the LDS dest must be linear.
    const int wbase = (wv < 2) ? wv * 128 : 256 + (wv - 2) * 112;

    auto stage = [&](float* lbuf, int chunk) {
        const size_t fbase = (size_t)chunk * (size_t)(CPB * NC);
        const float4* gp = reinterpret_cast<const float4*>(pred + fbase);
        const float4* gt = reinterpret_cast<const float4*>(targ + fbase);
        float4* lb = reinterpret_cast<float4*>(lbuf);
        const int s0 = wbase + ln;
        gload16(s0 < PREDS ? gp + s0 : gt + (s0 - PREDS), lb + s0);
        const int s1 = wbase + 64 + ln;
        if (wv < 2) {
            gload16(s1 < PREDS ? gp + s1 : gt + (s1 - PREDS), lb + s1);
        } else if (ln < 48) {
            gload16(gt + (s1 - PREDS), lb + s1);   // s1 >= 320 -> always targ
        }
    };

    const int n = (NCHT - bid + GRID - 1) / GRID;   // 9 (bid<256) or 8

    // prologue: fill buffers 0,1 (4 outstanding/wave); wait oldest 2 -> buf0 ok
    stage(sbuf, bid);
    stage(sbuf + FPBF, bid + GRID);
    asm volatile("s_waitcnt vmcnt(2)" ::: "memory");
    __builtin_amdgcn_sched_barrier(0);
    __builtin_amdgcn_s_barrier();
    __builtin_amdgcn_sched_barrier(0);

    float acc = 0.0f;
    for (int k = 0; k < n; ++k) {
        const bool pre = (k + 2 < n);
        if (pre) stage(sbuf + ((k + 2) % 3) * FPBF, bid + (k + 2) * GRID);

        if (tid < CPB) {
            const float* b = sbuf + (k % 3) * FPBF;
            acc += cell_loss(b + tid * NC, b + CPB * NC + tid * NC);
        }

        // certify buf[k+1] complete; keep buf[k+2]'s 2 loads in flight
        if (pre) asm volatile("s_waitcnt vmcnt(2)" ::: "memory");
        else     asm volatile("s_waitcnt vmcnt(0)" ::: "memory");
        __builtin_amdgcn_sched_barrier(0);
        __builtin_amdgcn_s_barrier();
        __builtin_amdgcn_sched_barrier(0);
    }

    // block reduction -> partial[bid]
    __shared__ float wsum[BLOCK / 64];
    #pragma unroll
    for (int o = 32; o > 0; o >>= 1) acc += __shfl_down(acc, o, 64);
    if ((tid & 63) == 0) wsum[tid >> 6] = acc;
    __syncthreads();
    if (tid == 0)
        partial[bid] = wsum[0] + wsum[1] + wsum[2] + wsum[3];
}

__global__ __launch_bounds__(64)
void yolo_final(const float* __restrict__ partial, float* __restrict__ out)
{
    const int tid = threadIdx.x;
    double s = 0.0;
    #pragma unroll
    for (int i = 0; i < GRID / 64; ++i) s += (double)partial[tid + i * 64];
    #pragma unroll
    for (int o = 32; o > 0; o >>= 1) s += __shfl_down(s, o, 64);
    if (tid == 0) out[0] = (float)(s / (double)N_IMG);
}

extern "C" void kernel_launch(void* const* d_in, const int* in_sizes, int n_in,
                              void* d_out, int out_size, void* d_ws, size_t ws_size,
                              hipStream_t stream)
{
    const float* pred = (const float*)d_in[0];
    const float* targ = (const float*)d_in[1];
    float* out        = (float*)d_out;
    float* partial    = (float*)d_ws;   // 1536 floats = 6 KB

    yolo_main<<<GRID, BLOCK, 0, stream>>>(pred, targ, partial);
    yolo_final<<<1, 64, 0, stream>>>(partial, out);
}